// Round 15
// baseline (38.491 us; speedup 1.0000x reference)
//
#include <hip/hip_runtime.h>
#include <stdint.h>

// SWF2LUT 4-simplex interpolation, mode 's'.
// img_in: (8,1,513,513) f32, integer values 0..255
// weight: (17^4, 3) f32  -> quantized clip(round(w*127),-127,127)
// out:    (8,1,512,512,3) f32
//
// Round-15 = round-14 (2-phase u16 LDS-gather, clamp+late-fixup, packed
// accumulators, __launch_bounds__(1024,4)) + ONE change: T14 async-stage
// split for the fill-B plane. The 96 KiB ch2 read is issued into registers
// right after the fill-A barrier and written to LDS only after phase A
// completes -> the exposed ~1.9us L2-read bubble between the two gather
// phases is hidden under phase A's LDS/VALU work. (+24 VGPR, ~85 live peak,
// within the 128 budget; this prefetch was benign in round 12 — the poison
// there was the per-iteration rare branch, removed in round 14.)

#define LQ   17
#define L2C  (17 * 17)        // 289
#define L3C  (17 * 17 * 17)   // 4913
#define NENT (L3C * 17)       // 83521
#define SUMSTRIDE (L3C + L2C + LQ + 1)  // 5220 (constant full-path offset)

#define LDSA_ENTRIES 81920    // u16 entries resident in phase A (160 KiB)
#define LDSA_BYTES   163840
#define RARE_BASE    (LDSA_ENTRIES - SUMSTRIDE)  // 76700: base>=this -> rare
#define P16_ENTRIES  83968    // u16 plane padded (167936 B, mult of 16)
#define CH2_BYTES    98304    // ch2 u8 plane padded to 96 KiB

// ---- stage 1: quantize weights into u16(ch0,ch1) plane + ch2 u8 plane ----
__global__ __launch_bounds__(256) void quant_split_kernel(
    const float* __restrict__ w, uint16_t* __restrict__ p16,
    char* __restrict__ ch2) {
    int e = blockIdx.x * 256 + threadIdx.x;   // 0..98303
    if (e < NENT) {
        int q0 = (int)rintf(w[e * 3 + 0] * 127.0f);  // round-half-even
        int q1 = (int)rintf(w[e * 3 + 1] * 127.0f);
        int q2 = (int)rintf(w[e * 3 + 2] * 127.0f);
        q0 = min(127, max(-127, q0));
        q1 = min(127, max(-127, q1));
        q2 = min(127, max(-127, q2));
        p16[e] = (uint16_t)((q0 & 0xFF) | ((q1 & 0xFF) << 8));
        ch2[e] = (char)q2;
    } else {
        if (e < P16_ENTRIES) p16[e] = 0;
        ch2[e] = 0;
    }
}

__device__ __forceinline__ int stride_of(int j) {
    // strides[j] = 17^(3-j); cndmask chain, no runtime-indexed array
    return j == 0 ? L3C : (j == 1 ? L2C : (j == 2 ? LQ : 1));
}

// 9 consecutive floats with only 4B alignment guaranteed: packed float4
struct __attribute__((packed, aligned(4))) f4p { float a, b, c, d; };
__device__ __forceinline__ void load9(const float* p, float v[9]) {
    const f4p* q = (const f4p*)p;
    f4p A = q[0], B = q[1];
    v[0] = A.a; v[1] = A.b; v[2] = A.c; v[3] = A.d;
    v[4] = B.a; v[5] = B.b; v[6] = B.c; v[7] = B.d;
    v[8] = p[8];
}

// packed-int16 accumulator extract -> final float (exact /16)
__device__ __forceinline__ float exlo(int x) {
    return (float)((x << 16) >> 16) * 0.0625f;
}
__device__ __forceinline__ float exhi(int x) {
    return (float)(x >> 16) * 0.0625f;
}

// ---- main fused kernel: 256 WGs x 1024 threads, 8 px/thread ----
extern __shared__ char lut[];

__global__ __launch_bounds__(1024, 4) void interp_fused16_kernel(
    const float* __restrict__ img, const uint16_t* __restrict__ p16,
    const char* __restrict__ ch2, float* __restrict__ out) {
    int G = blockIdx.x * 1024 + threadIdx.x;   // 0..262143, 8 px each
    int x0 = (G & 63) << 3;                    // 0..504 step 8
    int y  = (G >> 6) & 511;
    int im = G >> 15;                          // 0..7

    // ---- phase 0: img load (vectorized) + sort ONCE; packed VGPR state ----
    const float* r0 = img + im * (513 * 513) + y * 513 + x0;
    float v0[9], v1[9];
    load9(r0, v0);
    load9(r0 + 513, v1);

    int pi0[8], pk1[8], pk2[8];
#pragma unroll
    for (int i = 0; i < 8; ++i) {
        int a = (int)v0[i], b = (int)v0[i + 1];
        int c = (int)v1[i], d = (int)v1[i + 1];
        int base = (a >> 4) * L3C + (b >> 4) * L2C + (c >> 4) * LQ + (d >> 4);
        // keys: f*4 + coord_index (replicates argsort(-tie_key))
        int k0 = ((a & 15) << 2) | 0;
        int k1 = ((b & 15) << 2) | 1;
        int k2 = ((c & 15) << 2) | 2;
        int k3 = ((d & 15) << 2) | 3;
        int t;
        if (k0 < k1) { t = k0; k0 = k1; k1 = t; }
        if (k2 < k3) { t = k2; k2 = k3; k3 = t; }
        if (k0 < k2) { t = k0; k0 = k2; k2 = t; }
        if (k1 < k3) { t = k1; k1 = k3; k3 = t; }
        if (k1 < k2) { t = k1; k1 = k2; k2 = t; }
        int fs0 = k0 >> 2, fs1 = k1 >> 2, fs2 = k2 >> 2, fs3 = k3 >> 2;
        int s0 = stride_of(k0 & 3);               // <= 4913 (13 bits)
        int s01 = s0 + stride_of(k1 & 3);         // <= 5202 (13 bits)
        int s012 = s01 + stride_of(k2 & 3);       // <= 5219 (13 bits)
        pi0[i] = base;
        pk1[i] = s0 | (s01 << 13);
        pk2[i] = (fs0 << 12) | (fs1 << 8) | (fs2 << 4) | fs3 | (s012 << 16);
    }

    // ---- fill LDS-A: u16 plane entries [0, 81920) = 160 KiB ----
    {
        const uint4* src = (const uint4*)p16;
        uint4* dst = (uint4*)lut;
#pragma unroll
        for (int k = 0; k < 10; ++k)
            dst[threadIdx.x + k * 1024] = src[threadIdx.x + k * 1024];
    }
    __syncthreads();

    // ---- T14: issue ch2 plane loads NOW; they complete under phase A ----
    const uint4* c2src = (const uint4*)ch2;
    uint4 pf0 = c2src[threadIdx.x];
    uint4 pf1 = c2src[threadIdx.x + 1024];
    uint4 pf2 = c2src[threadIdx.x + 2048];
    uint4 pf3 = c2src[threadIdx.x + 3072];
    uint4 pf4 = c2src[threadIdx.x + 4096];
    uint4 pf5 = c2src[threadIdx.x + 5120];

    // ---- phase A: 5 clamped u16 LDS gathers/px -> ch0 and ch1 ----
    const uint16_t* t16 = (const uint16_t*)lut;
    int racc0[4] = {0, 0, 0, 0};
    int racc1[4] = {0, 0, 0, 0};
#pragma unroll
    for (int i = 0; i < 8; ++i) {
        int fs = pk2[i];
        int fs0 = (fs >> 12) & 15, fs1 = (fs >> 8) & 15;
        int fs2 = (fs >> 4) & 15,  fs3 = fs & 15;
        int i0 = pi0[i];                               // <= 78300, in range
        int i1 = min(i0 + (pk1[i] & 0x1FFF), LDSA_ENTRIES - 1);
        int i2 = min(i0 + (pk1[i] >> 13), LDSA_ENTRIES - 1);
        int i3 = min(i0 + ((fs >> 16) & 0x1FFF), LDSA_ENTRIES - 1);
        int i4 = min(i0 + SUMSTRIDE, LDSA_ENTRIES - 1);
        int u0 = t16[i0], u1 = t16[i1], u2 = t16[i2], u3 = t16[i3],
            u4 = t16[i4];
        int w0 = 16 - fs0, w1 = fs0 - fs1, w2 = fs1 - fs2, w3 = fs2 - fs3,
            w4 = fs3;
        int a0 = w0 * ((int)(u0 << 24) >> 24) + w1 * ((int)(u1 << 24) >> 24) +
                 w2 * ((int)(u2 << 24) >> 24) + w3 * ((int)(u3 << 24) >> 24) +
                 w4 * ((int)(u4 << 24) >> 24);
        int a1 = w0 * ((int)(u0 << 16) >> 24) + w1 * ((int)(u1 << 16) >> 24) +
                 w2 * ((int)(u2 << 16) >> 24) + w3 * ((int)(u3 << 16) >> 24) +
                 w4 * ((int)(u4 << 16) >> 24);
        racc0[i >> 1] |= (a0 & 0xFFFF) << (16 * (i & 1));
        racc1[i >> 1] |= (a1 & 0xFFFF) << (16 * (i & 1));
    }

    // ---- fixup (packed halves; ~2.2% px, exec-masked, once) ----
#pragma unroll
    for (int i = 0; i < 8; ++i) {
        if (pi0[i] >= RARE_BASE) {
            int fs = pk2[i];
            int fs0 = (fs >> 12) & 15, fs1 = (fs >> 8) & 15;
            int fs2 = (fs >> 4) & 15,  fs3 = fs & 15;
            int i0 = pi0[i];
            int u0 = p16[i0];
            int u1 = p16[i0 + (pk1[i] & 0x1FFF)];
            int u2 = p16[i0 + (pk1[i] >> 13)];
            int u3 = p16[i0 + ((fs >> 16) & 0x1FFF)];
            int u4 = p16[i0 + SUMSTRIDE];
            int w0 = 16 - fs0, w1 = fs0 - fs1, w2 = fs1 - fs2,
                w3 = fs2 - fs3, w4 = fs3;
            int a0 = w0 * ((int)(u0 << 24) >> 24) +
                     w1 * ((int)(u1 << 24) >> 24) +
                     w2 * ((int)(u2 << 24) >> 24) +
                     w3 * ((int)(u3 << 24) >> 24) +
                     w4 * ((int)(u4 << 24) >> 24);
            int a1 = w0 * ((int)(u0 << 16) >> 24) +
                     w1 * ((int)(u1 << 16) >> 24) +
                     w2 * ((int)(u2 << 16) >> 24) +
                     w3 * ((int)(u3 << 16) >> 24) +
                     w4 * ((int)(u4 << 16) >> 24);
            int sh = 16 * (i & 1);
            racc0[i >> 1] = (racc0[i >> 1] & ~(0xFFFF << sh)) |
                            ((a0 & 0xFFFF) << sh);
            racc1[i >> 1] = (racc1[i >> 1] & ~(0xFFFF << sh)) |
                            ((a1 & 0xFFFF) << sh);
        }
    }
    __syncthreads();   // phase A gathers done before LDS overwrite

    // ---- write prefetched ch2 plane into LDS (write-only fill) ----
    {
        uint4* dst = (uint4*)lut;
        dst[threadIdx.x]        = pf0;
        dst[threadIdx.x + 1024] = pf1;
        dst[threadIdx.x + 2048] = pf2;
        dst[threadIdx.x + 3072] = pf3;
        dst[threadIdx.x + 4096] = pf4;
        dst[threadIdx.x + 5120] = pf5;
    }
    __syncthreads();

    // ---- phase B: 5 u8 gathers/px -> ch2 (full plane, no clamps) ----
    const signed char* t8 = (const signed char*)lut;
    int racc2[4] = {0, 0, 0, 0};
#pragma unroll
    for (int i = 0; i < 8; ++i) {
        int fs = pk2[i];
        int fs0 = (fs >> 12) & 15, fs1 = (fs >> 8) & 15;
        int fs2 = (fs >> 4) & 15,  fs3 = fs & 15;
        int i0 = pi0[i];
        int p0 = t8[i0];
        int p1 = t8[i0 + (pk1[i] & 0x1FFF)];
        int p2 = t8[i0 + (pk1[i] >> 13)];
        int p3 = t8[i0 + ((fs >> 16) & 0x1FFF)];
        int p4 = t8[i0 + SUMSTRIDE];
        int acc = (16 - fs0) * p0 + (fs0 - fs1) * p1 + (fs1 - fs2) * p2 +
                  (fs2 - fs3) * p3 + fs3 * p4;
        racc2[i >> 1] |= (acc & 0xFFFF) << (16 * (i & 1));
    }
    // pi0/pk1/pk2 dead here.

    // ---- store: 6 float4 built directly from the 12 packed accumulators ---
    int opix = ((im * 512 + y) * 512 + x0) * 3;  // mult of 24 -> 96B aligned
    float4* o = (float4*)(out + opix);
    o[0] = make_float4(exlo(racc0[0]), exlo(racc1[0]), exlo(racc2[0]),
                       exhi(racc0[0]));
    o[1] = make_float4(exhi(racc1[0]), exhi(racc2[0]), exlo(racc0[1]),
                       exlo(racc1[1]));
    o[2] = make_float4(exlo(racc2[1]), exhi(racc0[1]), exhi(racc1[1]),
                       exhi(racc2[1]));
    o[3] = make_float4(exlo(racc0[2]), exlo(racc1[2]), exlo(racc2[2]),
                       exhi(racc0[2]));
    o[4] = make_float4(exhi(racc1[2]), exhi(racc2[2]), exlo(racc0[3]),
                       exlo(racc1[3]));
    o[5] = make_float4(exlo(racc2[3]), exhi(racc0[3]), exhi(racc1[3]),
                       exhi(racc2[3]));
}

// ================== fallback: round-11 proven kernel ==================
#define PLANE_STRIDE 83584
#define LDS8_BYTES   83584

__global__ __launch_bounds__(256) void quant_planar_kernel(
    const float* __restrict__ w, char* __restrict__ planes, int n) {
    int e = blockIdx.x * 256 + threadIdx.x;
    if (e >= n) return;
#pragma unroll
    for (int ch = 0; ch < 3; ++ch) {
        int q = (int)rintf(w[e * 3 + ch] * 127.0f);
        q = min(127, max(-127, q));
        planes[ch * PLANE_STRIDE + e] = (char)q;
    }
}

__global__ __launch_bounds__(1024, 4) void interp_fused8_kernel(
    const float* __restrict__ img, const char* __restrict__ planes,
    float* __restrict__ out) {
    int G = blockIdx.x * 1024 + threadIdx.x;
    int x0 = (G & 63) << 3;
    int y  = (G >> 6) & 511;
    int im = G >> 15;

    const float* r0 = img + im * (513 * 513) + y * 513 + x0;
    float v0[9], v1[9];
    load9(r0, v0);
    load9(r0 + 513, v1);

    int pi0[8], pk1[8], pk2[8];
#pragma unroll
    for (int i = 0; i < 8; ++i) {
        int a = (int)v0[i], b = (int)v0[i + 1];
        int c = (int)v1[i], d = (int)v1[i + 1];
        int base = (a >> 4) * L3C + (b >> 4) * L2C + (c >> 4) * LQ + (d >> 4);
        int k0 = ((a & 15) << 2) | 0;
        int k1 = ((b & 15) << 2) | 1;
        int k2 = ((c & 15) << 2) | 2;
        int k3 = ((d & 15) << 2) | 3;
        int t;
        if (k0 < k1) { t = k0; k0 = k1; k1 = t; }
        if (k2 < k3) { t = k2; k2 = k3; k3 = t; }
        if (k0 < k2) { t = k0; k0 = k2; k2 = t; }
        if (k1 < k3) { t = k1; k1 = k3; k3 = t; }
        if (k1 < k2) { t = k1; k1 = k2; k2 = t; }
        int fs0 = k0 >> 2, fs1 = k1 >> 2, fs2 = k2 >> 2, fs3 = k3 >> 2;
        int s0 = stride_of(k0 & 3);
        int s01 = s0 + stride_of(k1 & 3);
        int s012 = s01 + stride_of(k2 & 3);
        pi0[i] = base;
        pk1[i] = s0 | (s01 << 13);
        pk2[i] = (fs0 << 12) | (fs1 << 8) | (fs2 << 4) | fs3 | (s012 << 16);
    }

    int racc[3][4];
#pragma unroll
    for (int ch = 0; ch < 3; ++ch)
#pragma unroll
        for (int p = 0; p < 4; ++p) racc[ch][p] = 0;

#pragma unroll
    for (int ch = 0; ch < 3; ++ch) {
        __syncthreads();
        {
            const uint4* src =
                (const uint4*)(planes + (size_t)ch * PLANE_STRIDE);
            uint4* dst = (uint4*)lut;
            for (int k = threadIdx.x; k < PLANE_STRIDE / 16; k += 1024)
                dst[k] = src[k];
        }
        __syncthreads();
        const signed char* t8 = (const signed char*)lut;
#pragma unroll
        for (int i = 0; i < 8; ++i) {
            int fs = pk2[i];
            int fs0 = (fs >> 12) & 15, fs1 = (fs >> 8) & 15;
            int fs2 = (fs >> 4) & 15,  fs3 = fs & 15;
            int i0 = pi0[i];
            int p0 = t8[i0];
            int p1 = t8[i0 + (pk1[i] & 0x1FFF)];
            int p2 = t8[i0 + (pk1[i] >> 13)];
            int p3 = t8[i0 + ((fs >> 16) & 0x1FFF)];
            int p4 = t8[i0 + SUMSTRIDE];
            int acc = (16 - fs0) * p0 + (fs0 - fs1) * p1 + (fs1 - fs2) * p2 +
                      (fs2 - fs3) * p3 + fs3 * p4;
            racc[ch][i >> 1] |= (acc & 0xFFFF) << (16 * (i & 1));
        }
    }

    int opix = ((im * 512 + y) * 512 + x0) * 3;
    float4* o = (float4*)(out + opix);
    o[0] = make_float4(exlo(racc[0][0]), exlo(racc[1][0]), exlo(racc[2][0]),
                       exhi(racc[0][0]));
    o[1] = make_float4(exhi(racc[1][0]), exhi(racc[2][0]), exlo(racc[0][1]),
                       exlo(racc[1][1]));
    o[2] = make_float4(exlo(racc[2][1]), exhi(racc[0][1]), exhi(racc[1][1]),
                       exhi(racc[2][1]));
    o[3] = make_float4(exlo(racc[0][2]), exlo(racc[1][2]), exlo(racc[2][2]),
                       exhi(racc[0][2]));
    o[4] = make_float4(exhi(racc[1][2]), exhi(racc[2][2]), exlo(racc[0][3]),
                       exlo(racc[1][3]));
    o[5] = make_float4(exlo(racc[2][3]), exhi(racc[0][3]), exhi(racc[1][3]),
                       exhi(racc[2][3]));
}

extern "C" void kernel_launch(void* const* d_in, const int* in_sizes, int n_in,
                              void* d_out, int out_size, void* d_ws,
                              size_t ws_size, hipStream_t stream) {
    const float* img = (const float*)d_in[0];
    const float* wgt = (const float*)d_in[1];
    float* out = (float*)d_out;

    // --- preferred: clamped 2-phase u16 kernel, 160 KiB dynamic LDS ---
    const size_t p16_bytes = (size_t)P16_ENTRIES * 2;     // 167936
    const size_t need16 = p16_bytes + CH2_BYTES;
    bool ok16 = (ws_size >= need16) && (d_ws != nullptr);
    if (ok16) {
        hipError_t e = hipFuncSetAttribute(
            reinterpret_cast<const void*>(interp_fused16_kernel),
            hipFuncAttributeMaxDynamicSharedMemorySize, LDSA_BYTES);
        ok16 = (e == hipSuccess);
    }
    if (ok16) {
        uint16_t* p16 = (uint16_t*)d_ws;
        char* ch2 = (char*)d_ws + p16_bytes;
        quant_split_kernel<<<CH2_BYTES / 256, 256, 0, stream>>>(wgt, p16,
                                                                ch2);
        interp_fused16_kernel<<<256, 1024, LDSA_BYTES, stream>>>(img, p16,
                                                                 ch2, out);
        return;
    }

    // --- fallback: round-11 proven kernel (83.5 KiB LDS) ---
    const size_t planes_bytes = (size_t)3 * PLANE_STRIDE;
    bool ok8 = (ws_size >= planes_bytes) && (d_ws != nullptr);
    if (ok8) {
        hipError_t e = hipFuncSetAttribute(
            reinterpret_cast<const void*>(interp_fused8_kernel),
            hipFuncAttributeMaxDynamicSharedMemorySize, LDS8_BYTES);
        ok8 = (e == hipSuccess);
    }
    if (ok8) {
        char* planes = (char*)d_ws;
        quant_planar_kernel<<<(NENT + 255) / 256, 256, 0, stream>>>(
            wgt, planes, NENT);
        interp_fused8_kernel<<<256, 1024, LDS8_BYTES, stream>>>(img, planes,
                                                                out);
    }
}

// Round 16
// 33.862 us; speedup vs baseline: 1.1367x; 1.1367x over previous
//
#include <hip/hip_runtime.h>
#include <stdint.h>

// SWF2LUT 4-simplex interpolation, mode 's'.
// img_in: (8,1,513,513) f32, integer values 0..255
// weight: (17^4, 3) f32  -> quantized clip(round(w*127),-127,127)
// out:    (8,1,512,512,3) f32
//
// FINAL (= round-14, the measured optimum at 33.9us; round-15's T14
// prefetch variant regressed to 38.5us and is reverted).
// Structure: 2-phase u16 LDS-gather. Phase A gathers ch0+ch1 as one u16/tap
// from a 160 KiB LDS window [0,81920) with clamped indices (branch-free);
// the ~2.2% rare pixels (base >= 76700) are fixed up once, exec-masked, on
// the packed int16 accumulators right after phase A. Phase B refills LDS
// with the full ch2 u8 plane and gathers without clamps. Sort runs once per
// pixel (packed 3-reg state); output is written once, coalesced, built
// directly from packed accumulators. __launch_bounds__(1024,4) gives the
// 128-VGPR budget matching the 1-WG/CU occupancy that 160 KiB LDS forces.

#define LQ   17
#define L2C  (17 * 17)        // 289
#define L3C  (17 * 17 * 17)   // 4913
#define NENT (L3C * 17)       // 83521
#define SUMSTRIDE (L3C + L2C + LQ + 1)  // 5220 (constant full-path offset)

#define LDSA_ENTRIES 81920    // u16 entries resident in phase A (160 KiB)
#define LDSA_BYTES   163840
#define RARE_BASE    (LDSA_ENTRIES - SUMSTRIDE)  // 76700: base>=this -> rare
#define P16_ENTRIES  83968    // u16 plane padded (167936 B, mult of 16)
#define CH2_BYTES    98304    // ch2 u8 plane padded to 96 KiB

// ---- stage 1: quantize weights into u16(ch0,ch1) plane + ch2 u8 plane ----
__global__ __launch_bounds__(256) void quant_split_kernel(
    const float* __restrict__ w, uint16_t* __restrict__ p16,
    char* __restrict__ ch2) {
    int e = blockIdx.x * 256 + threadIdx.x;   // 0..98303
    if (e < NENT) {
        int q0 = (int)rintf(w[e * 3 + 0] * 127.0f);  // round-half-even
        int q1 = (int)rintf(w[e * 3 + 1] * 127.0f);
        int q2 = (int)rintf(w[e * 3 + 2] * 127.0f);
        q0 = min(127, max(-127, q0));
        q1 = min(127, max(-127, q1));
        q2 = min(127, max(-127, q2));
        p16[e] = (uint16_t)((q0 & 0xFF) | ((q1 & 0xFF) << 8));
        ch2[e] = (char)q2;
    } else {
        if (e < P16_ENTRIES) p16[e] = 0;
        ch2[e] = 0;
    }
}

__device__ __forceinline__ int stride_of(int j) {
    // strides[j] = 17^(3-j); cndmask chain, no runtime-indexed array
    return j == 0 ? L3C : (j == 1 ? L2C : (j == 2 ? LQ : 1));
}

// 9 consecutive floats with only 4B alignment guaranteed: packed float4
struct __attribute__((packed, aligned(4))) f4p { float a, b, c, d; };
__device__ __forceinline__ void load9(const float* p, float v[9]) {
    const f4p* q = (const f4p*)p;
    f4p A = q[0], B = q[1];
    v[0] = A.a; v[1] = A.b; v[2] = A.c; v[3] = A.d;
    v[4] = B.a; v[5] = B.b; v[6] = B.c; v[7] = B.d;
    v[8] = p[8];
}

// packed-int16 accumulator extract -> final float (exact /16)
__device__ __forceinline__ float exlo(int x) {
    return (float)((x << 16) >> 16) * 0.0625f;
}
__device__ __forceinline__ float exhi(int x) {
    return (float)(x >> 16) * 0.0625f;
}

// ---- main fused kernel: 256 WGs x 1024 threads, 8 px/thread ----
extern __shared__ char lut[];

__global__ __launch_bounds__(1024, 4) void interp_fused16_kernel(
    const float* __restrict__ img, const uint16_t* __restrict__ p16,
    const char* __restrict__ ch2, float* __restrict__ out) {
    int G = blockIdx.x * 1024 + threadIdx.x;   // 0..262143, 8 px each
    int x0 = (G & 63) << 3;                    // 0..504 step 8
    int y  = (G >> 6) & 511;
    int im = G >> 15;                          // 0..7

    // ---- phase 0: img load (vectorized) + sort ONCE; packed VGPR state ----
    const float* r0 = img + im * (513 * 513) + y * 513 + x0;
    float v0[9], v1[9];
    load9(r0, v0);
    load9(r0 + 513, v1);

    int pi0[8], pk1[8], pk2[8];
#pragma unroll
    for (int i = 0; i < 8; ++i) {
        int a = (int)v0[i], b = (int)v0[i + 1];
        int c = (int)v1[i], d = (int)v1[i + 1];
        int base = (a >> 4) * L3C + (b >> 4) * L2C + (c >> 4) * LQ + (d >> 4);
        // keys: f*4 + coord_index (replicates argsort(-tie_key))
        int k0 = ((a & 15) << 2) | 0;
        int k1 = ((b & 15) << 2) | 1;
        int k2 = ((c & 15) << 2) | 2;
        int k3 = ((d & 15) << 2) | 3;
        int t;
        if (k0 < k1) { t = k0; k0 = k1; k1 = t; }
        if (k2 < k3) { t = k2; k2 = k3; k3 = t; }
        if (k0 < k2) { t = k0; k0 = k2; k2 = t; }
        if (k1 < k3) { t = k1; k1 = k3; k3 = t; }
        if (k1 < k2) { t = k1; k1 = k2; k2 = t; }
        int fs0 = k0 >> 2, fs1 = k1 >> 2, fs2 = k2 >> 2, fs3 = k3 >> 2;
        int s0 = stride_of(k0 & 3);               // <= 4913 (13 bits)
        int s01 = s0 + stride_of(k1 & 3);         // <= 5202 (13 bits)
        int s012 = s01 + stride_of(k2 & 3);       // <= 5219 (13 bits)
        pi0[i] = base;
        pk1[i] = s0 | (s01 << 13);
        pk2[i] = (fs0 << 12) | (fs1 << 8) | (fs2 << 4) | fs3 | (s012 << 16);
    }

    // ---- fill LDS-A: u16 plane entries [0, 81920) = 160 KiB ----
    {
        const uint4* src = (const uint4*)p16;
        uint4* dst = (uint4*)lut;
#pragma unroll
        for (int k = 0; k < 10; ++k)
            dst[threadIdx.x + k * 1024] = src[threadIdx.x + k * 1024];
    }
    __syncthreads();

    // ---- phase A: 5 clamped u16 LDS gathers/px -> ch0 and ch1 ----
    const uint16_t* t16 = (const uint16_t*)lut;
    int racc0[4] = {0, 0, 0, 0};
    int racc1[4] = {0, 0, 0, 0};
#pragma unroll
    for (int i = 0; i < 8; ++i) {
        int fs = pk2[i];
        int fs0 = (fs >> 12) & 15, fs1 = (fs >> 8) & 15;
        int fs2 = (fs >> 4) & 15,  fs3 = fs & 15;
        int i0 = pi0[i];                               // <= 78300, in range
        int i1 = min(i0 + (pk1[i] & 0x1FFF), LDSA_ENTRIES - 1);
        int i2 = min(i0 + (pk1[i] >> 13), LDSA_ENTRIES - 1);
        int i3 = min(i0 + ((fs >> 16) & 0x1FFF), LDSA_ENTRIES - 1);
        int i4 = min(i0 + SUMSTRIDE, LDSA_ENTRIES - 1);
        int u0 = t16[i0], u1 = t16[i1], u2 = t16[i2], u3 = t16[i3],
            u4 = t16[i4];
        int w0 = 16 - fs0, w1 = fs0 - fs1, w2 = fs1 - fs2, w3 = fs2 - fs3,
            w4 = fs3;
        int a0 = w0 * ((int)(u0 << 24) >> 24) + w1 * ((int)(u1 << 24) >> 24) +
                 w2 * ((int)(u2 << 24) >> 24) + w3 * ((int)(u3 << 24) >> 24) +
                 w4 * ((int)(u4 << 24) >> 24);
        int a1 = w0 * ((int)(u0 << 16) >> 24) + w1 * ((int)(u1 << 16) >> 24) +
                 w2 * ((int)(u2 << 16) >> 24) + w3 * ((int)(u3 << 16) >> 24) +
                 w4 * ((int)(u4 << 16) >> 24);
        racc0[i >> 1] |= (a0 & 0xFFFF) << (16 * (i & 1));
        racc1[i >> 1] |= (a1 & 0xFFFF) << (16 * (i & 1));
    }

    // ---- fixup NOW (packed halves; ~2.2% px, exec-masked): state liveness
    //      stays bounded by phase B, not by the store epilogue ----
#pragma unroll
    for (int i = 0; i < 8; ++i) {
        if (pi0[i] >= RARE_BASE) {
            int fs = pk2[i];
            int fs0 = (fs >> 12) & 15, fs1 = (fs >> 8) & 15;
            int fs2 = (fs >> 4) & 15,  fs3 = fs & 15;
            int i0 = pi0[i];
            int u0 = p16[i0];
            int u1 = p16[i0 + (pk1[i] & 0x1FFF)];
            int u2 = p16[i0 + (pk1[i] >> 13)];
            int u3 = p16[i0 + ((fs >> 16) & 0x1FFF)];
            int u4 = p16[i0 + SUMSTRIDE];
            int w0 = 16 - fs0, w1 = fs0 - fs1, w2 = fs1 - fs2,
                w3 = fs2 - fs3, w4 = fs3;
            int a0 = w0 * ((int)(u0 << 24) >> 24) +
                     w1 * ((int)(u1 << 24) >> 24) +
                     w2 * ((int)(u2 << 24) >> 24) +
                     w3 * ((int)(u3 << 24) >> 24) +
                     w4 * ((int)(u4 << 24) >> 24);
            int a1 = w0 * ((int)(u0 << 16) >> 24) +
                     w1 * ((int)(u1 << 16) >> 24) +
                     w2 * ((int)(u2 << 16) >> 24) +
                     w3 * ((int)(u3 << 16) >> 24) +
                     w4 * ((int)(u4 << 16) >> 24);
            int sh = 16 * (i & 1);
            racc0[i >> 1] = (racc0[i >> 1] & ~(0xFFFF << sh)) |
                            ((a0 & 0xFFFF) << sh);
            racc1[i >> 1] = (racc1[i >> 1] & ~(0xFFFF << sh)) |
                            ((a1 & 0xFFFF) << sh);
        }
    }
    __syncthreads();   // phase A gathers done before LDS overwrite

    // ---- fill LDS-B: ch2 u8 plane (96 KiB uniform copy) ----
    {
        const uint4* src = (const uint4*)ch2;
        uint4* dst = (uint4*)lut;
#pragma unroll
        for (int k = 0; k < 6; ++k)
            dst[threadIdx.x + k * 1024] = src[threadIdx.x + k * 1024];
    }
    __syncthreads();

    // ---- phase B: 5 u8 gathers/px -> ch2 (full plane, no clamps) ----
    const signed char* t8 = (const signed char*)lut;
    int racc2[4] = {0, 0, 0, 0};
#pragma unroll
    for (int i = 0; i < 8; ++i) {
        int fs = pk2[i];
        int fs0 = (fs >> 12) & 15, fs1 = (fs >> 8) & 15;
        int fs2 = (fs >> 4) & 15,  fs3 = fs & 15;
        int i0 = pi0[i];
        int p0 = t8[i0];
        int p1 = t8[i0 + (pk1[i] & 0x1FFF)];
        int p2 = t8[i0 + (pk1[i] >> 13)];
        int p3 = t8[i0 + ((fs >> 16) & 0x1FFF)];
        int p4 = t8[i0 + SUMSTRIDE];
        int acc = (16 - fs0) * p0 + (fs0 - fs1) * p1 + (fs1 - fs2) * p2 +
                  (fs2 - fs3) * p3 + fs3 * p4;
        racc2[i >> 1] |= (acc & 0xFFFF) << (16 * (i & 1));
    }
    // pi0/pk1/pk2 dead here.

    // ---- store: 6 float4 built directly from the 12 packed accumulators ---
    int opix = ((im * 512 + y) * 512 + x0) * 3;  // mult of 24 -> 96B aligned
    float4* o = (float4*)(out + opix);
    o[0] = make_float4(exlo(racc0[0]), exlo(racc1[0]), exlo(racc2[0]),
                       exhi(racc0[0]));
    o[1] = make_float4(exhi(racc1[0]), exhi(racc2[0]), exlo(racc0[1]),
                       exlo(racc1[1]));
    o[2] = make_float4(exlo(racc2[1]), exhi(racc0[1]), exhi(racc1[1]),
                       exhi(racc2[1]));
    o[3] = make_float4(exlo(racc0[2]), exlo(racc1[2]), exlo(racc2[2]),
                       exhi(racc0[2]));
    o[4] = make_float4(exhi(racc1[2]), exhi(racc2[2]), exlo(racc0[3]),
                       exlo(racc1[3]));
    o[5] = make_float4(exlo(racc2[3]), exhi(racc0[3]), exhi(racc1[3]),
                       exhi(racc2[3]));
}

// ================== fallback: round-11 proven kernel ==================
#define PLANE_STRIDE 83584
#define LDS8_BYTES   83584

__global__ __launch_bounds__(256) void quant_planar_kernel(
    const float* __restrict__ w, char* __restrict__ planes, int n) {
    int e = blockIdx.x * 256 + threadIdx.x;
    if (e >= n) return;
#pragma unroll
    for (int ch = 0; ch < 3; ++ch) {
        int q = (int)rintf(w[e * 3 + ch] * 127.0f);
        q = min(127, max(-127, q));
        planes[ch * PLANE_STRIDE + e] = (char)q;
    }
}

__global__ __launch_bounds__(1024, 4) void interp_fused8_kernel(
    const float* __restrict__ img, const char* __restrict__ planes,
    float* __restrict__ out) {
    int G = blockIdx.x * 1024 + threadIdx.x;
    int x0 = (G & 63) << 3;
    int y  = (G >> 6) & 511;
    int im = G >> 15;

    const float* r0 = img + im * (513 * 513) + y * 513 + x0;
    float v0[9], v1[9];
    load9(r0, v0);
    load9(r0 + 513, v1);

    int pi0[8], pk1[8], pk2[8];
#pragma unroll
    for (int i = 0; i < 8; ++i) {
        int a = (int)v0[i], b = (int)v0[i + 1];
        int c = (int)v1[i], d = (int)v1[i + 1];
        int base = (a >> 4) * L3C + (b >> 4) * L2C + (c >> 4) * LQ + (d >> 4);
        int k0 = ((a & 15) << 2) | 0;
        int k1 = ((b & 15) << 2) | 1;
        int k2 = ((c & 15) << 2) | 2;
        int k3 = ((d & 15) << 2) | 3;
        int t;
        if (k0 < k1) { t = k0; k0 = k1; k1 = t; }
        if (k2 < k3) { t = k2; k2 = k3; k3 = t; }
        if (k0 < k2) { t = k0; k0 = k2; k2 = t; }
        if (k1 < k3) { t = k1; k1 = k3; k3 = t; }
        if (k1 < k2) { t = k1; k1 = k2; k2 = t; }
        int fs0 = k0 >> 2, fs1 = k1 >> 2, fs2 = k2 >> 2, fs3 = k3 >> 2;
        int s0 = stride_of(k0 & 3);
        int s01 = s0 + stride_of(k1 & 3);
        int s012 = s01 + stride_of(k2 & 3);
        pi0[i] = base;
        pk1[i] = s0 | (s01 << 13);
        pk2[i] = (fs0 << 12) | (fs1 << 8) | (fs2 << 4) | fs3 | (s012 << 16);
    }

    int racc[3][4];
#pragma unroll
    for (int ch = 0; ch < 3; ++ch)
#pragma unroll
        for (int p = 0; p < 4; ++p) racc[ch][p] = 0;

#pragma unroll
    for (int ch = 0; ch < 3; ++ch) {
        __syncthreads();
        {
            const uint4* src =
                (const uint4*)(planes + (size_t)ch * PLANE_STRIDE);
            uint4* dst = (uint4*)lut;
            for (int k = threadIdx.x; k < PLANE_STRIDE / 16; k += 1024)
                dst[k] = src[k];
        }
        __syncthreads();
        const signed char* t8 = (const signed char*)lut;
#pragma unroll
        for (int i = 0; i < 8; ++i) {
            int fs = pk2[i];
            int fs0 = (fs >> 12) & 15, fs1 = (fs >> 8) & 15;
            int fs2 = (fs >> 4) & 15,  fs3 = fs & 15;
            int i0 = pi0[i];
            int p0 = t8[i0];
            int p1 = t8[i0 + (pk1[i] & 0x1FFF)];
            int p2 = t8[i0 + (pk1[i] >> 13)];
            int p3 = t8[i0 + ((fs >> 16) & 0x1FFF)];
            int p4 = t8[i0 + SUMSTRIDE];
            int acc = (16 - fs0) * p0 + (fs0 - fs1) * p1 + (fs1 - fs2) * p2 +
                      (fs2 - fs3) * p3 + fs3 * p4;
            racc[ch][i >> 1] |= (acc & 0xFFFF) << (16 * (i & 1));
        }
    }

    int opix = ((im * 512 + y) * 512 + x0) * 3;
    float4* o = (float4*)(out + opix);
    o[0] = make_float4(exlo(racc[0][0]), exlo(racc[1][0]), exlo(racc[2][0]),
                       exhi(racc[0][0]));
    o[1] = make_float4(exhi(racc[1][0]), exhi(racc[2][0]), exlo(racc[0][1]),
                       exlo(racc[1][1]));
    o[2] = make_float4(exlo(racc[2][1]), exhi(racc[0][1]), exhi(racc[1][1]),
                       exhi(racc[2][1]));
    o[3] = make_float4(exlo(racc[0][2]), exlo(racc[1][2]), exlo(racc[2][2]),
                       exhi(racc[0][2]));
    o[4] = make_float4(exhi(racc[1][2]), exhi(racc[2][2]), exlo(racc[0][3]),
                       exlo(racc[1][3]));
    o[5] = make_float4(exlo(racc[2][3]), exhi(racc[0][3]), exhi(racc[1][3]),
                       exhi(racc[2][3]));
}

extern "C" void kernel_launch(void* const* d_in, const int* in_sizes, int n_in,
                              void* d_out, int out_size, void* d_ws,
                              size_t ws_size, hipStream_t stream) {
    const float* img = (const float*)d_in[0];
    const float* wgt = (const float*)d_in[1];
    float* out = (float*)d_out;

    // --- preferred: clamped 2-phase u16 kernel, 160 KiB dynamic LDS ---
    const size_t p16_bytes = (size_t)P16_ENTRIES * 2;     // 167936
    const size_t need16 = p16_bytes + CH2_BYTES;
    bool ok16 = (ws_size >= need16) && (d_ws != nullptr);
    if (ok16) {
        hipError_t e = hipFuncSetAttribute(
            reinterpret_cast<const void*>(interp_fused16_kernel),
            hipFuncAttributeMaxDynamicSharedMemorySize, LDSA_BYTES);
        ok16 = (e == hipSuccess);
    }
    if (ok16) {
        uint16_t* p16 = (uint16_t*)d_ws;
        char* ch2 = (char*)d_ws + p16_bytes;
        quant_split_kernel<<<CH2_BYTES / 256, 256, 0, stream>>>(wgt, p16,
                                                                ch2);
        interp_fused16_kernel<<<256, 1024, LDSA_BYTES, stream>>>(img, p16,
                                                                 ch2, out);
        return;
    }

    // --- fallback: round-11 proven kernel (83.5 KiB LDS) ---
    const size_t planes_bytes = (size_t)3 * PLANE_STRIDE;
    bool ok8 = (ws_size >= planes_bytes) && (d_ws != nullptr);
    if (ok8) {
        hipError_t e = hipFuncSetAttribute(
            reinterpret_cast<const void*>(interp_fused8_kernel),
            hipFuncAttributeMaxDynamicSharedMemorySize, LDS8_BYTES);
        ok8 = (e == hipSuccess);
    }
    if (ok8) {
        char* planes = (char*)d_ws;
        quant_planar_kernel<<<(NENT + 255) / 256, 256, 0, stream>>>(
            wgt, planes, NENT);
        interp_fused8_kernel<<<256, 1024, LDS8_BYTES, stream>>>(img, planes,
                                                                out);
    }
}